// Round 4
// baseline (515.913 us; speedup 1.0000x reference)
//
#include <hip/hip_runtime.h>
#include <hip/hip_bf16.h>
#include <math.h>
#include <stdint.h>

#define NB 128     // batch (images and captions)
#define NR 36      // regions
#define NW 64      // words
#define ND 1024    // dim
#define MT 48      // NR padded to 3 MFMA m-tiles
#define EPSF 1e-8f
#define LAM_SM 9.0f
#define LAM_LSE 6.0f
#define MARGINF 0.2f

typedef _Float16 f16;
typedef f16 f16x4 __attribute__((ext_vector_type(4)));
typedef f16 f16x8 __attribute__((ext_vector_type(8)));
typedef float f32x4 __attribute__((ext_vector_type(4)));

// ---------------- kernel 0: fp32 -> f16 (im zero-padded to 48 rows) + ncap --------
__global__ __launch_bounds__(256) void convert_kernel(
    const float* __restrict__ im, const float* __restrict__ s,
    f16* __restrict__ im16, f16* __restrict__ s16, float* __restrict__ ncap) {
    __shared__ float wsum[4];
    const int b = blockIdx.x, row = blockIdx.y, t = threadIdx.x;
    if (row < MT) {
        f16x4* dst = (f16x4*)(im16 + ((size_t)b * MT + row) * ND);
        if (row < NR) {
            const float4* src = (const float4*)(im + ((size_t)b * NR + row) * ND);
            float4 v = src[t];
            f16x4 h = {(f16)v.x, (f16)v.y, (f16)v.z, (f16)v.w};
            dst[t] = h;
        } else {
            dst[t] = (f16x4){(f16)0.f, (f16)0.f, (f16)0.f, (f16)0.f};
        }
    } else {
        const int w = row - MT;
        const float4* src = (const float4*)(s + ((size_t)b * NW + w) * ND);
        float4 v = src[t];
        f16x4 h = {(f16)v.x, (f16)v.y, (f16)v.z, (f16)v.w};
        ((f16x4*)(s16 + ((size_t)b * NW + w) * ND))[t] = h;
        // fused caption-norm
        float ss = v.x * v.x + v.y * v.y + v.z * v.z + v.w * v.w;
        #pragma unroll
        for (int off = 1; off < 64; off <<= 1) ss += __shfl_xor(ss, off, 64);
        if ((t & 63) == 0) wsum[t >> 6] = ss;
        __syncthreads();
        if (t == 0) ncap[b * NW + w] = sqrtf(wsum[0] + wsum[1] + wsum[2] + wsum[3]);
    }
}

// ---------------- kernel A: per-image f16 Gram [48][64] via MFMA ------------------
__global__ __launch_bounds__(256) void gram16_kernel(
    const f16* __restrict__ im16, f16* __restrict__ Mg16) {
    const int b = blockIdx.x, mt = blockIdx.y;          // mt 0..2
    const int wave = threadIdx.x >> 6, lane = threadIdx.x & 63;
    const int quad = lane >> 4, l16 = lane & 15;
    const int nt = wave;                                 // n-tile 0..3
    const f16* Ab = im16 + (size_t)b * (MT * ND);
    f32x4 acc = (f32x4){0.f, 0.f, 0.f, 0.f};
    for (int kk = 0; kk < ND; kk += 32) {
        f16x8 af = *(const f16x8*)(Ab + (mt * 16 + l16) * ND + kk + quad * 8);
        f16x8 bf = *(const f16x8*)(Ab + (nt * 16 + l16) * ND + kk + quad * 8);
        acc = __builtin_amdgcn_mfma_f32_16x16x32_f16(af, bf, acc, 0, 0, 0);
    }
    f16* Mb = Mg16 + (size_t)b * (MT * NW);
    #pragma unroll
    for (int r = 0; r < 4; ++r) {
        int row = mt * 16 + quad * 4 + r;
        Mb[row * NW + nt * 16 + l16] = (f16)acc[r];
    }
}

// ---------------- kernel B: block = 2 images x 4 captions, no-LDS K-loop ----------
// LDS: per-wave 8KB E^T scratch (64 cols x 64 padded rows, f16, XOR-swizzled chunks)
__global__ __launch_bounds__(256, 3) void pair_mfma_kernel(
    const f16* __restrict__ im16, const f16* __restrict__ s16,
    const int* __restrict__ s_l, const f16* __restrict__ Mg16,
    const float* __restrict__ ncap, float* __restrict__ scores) {
    __shared__ __align__(16) char smemE[4 * 8192];
    const int t = threadIdx.x;
    const int wave = t >> 6, lane = t & 63;
    const int quad = lane >> 4, l16 = lane & 15;

    // XCD-aware swizzle: XCD x owns images [16x,16x+16); jg-major caption sweep.
    const int lin = blockIdx.x;          // 0..2047
    const int xcd = lin & 7, k = lin >> 3;
    const int jg = k >> 3;               // 0..31
    const int ip = (xcd << 3) | (k & 7); // 0..63
    const int i0 = ip * 2, i1 = i0 + 1;
    const int j = jg * 4 + wave;         // this wave's caption
    const int L = s_l[j];

    const f16* A0 = im16 + (size_t)i0 * (MT * ND);
    const f16* A1 = im16 + (size_t)i1 * (MT * ND);
    const f16* Bb = s16 + (size_t)j * (NW * ND);
    const int rowOffA = l16 * ND + quad * 8;   // + mi*16*ND + kk

    f32x4 acc[2][3][4];
    #pragma unroll
    for (int g = 0; g < 2; ++g)
        #pragma unroll
        for (int mi = 0; mi < 3; ++mi)
            #pragma unroll
            for (int nt = 0; nt < 4; ++nt)
                acc[g][mi][nt] = (f32x4){0.f, 0.f, 0.f, 0.f};

    // ---- K-loop: pure global(L2) loads + MFMA, no LDS, no barriers ----
    for (int kk = 0; kk < ND; kk += 32) {
        f16x8 bfr[4], a0r[3], a1r[3];
        #pragma unroll
        for (int nt = 0; nt < 4; ++nt)
            bfr[nt] = *(const f16x8*)(Bb + nt * 16 * ND + rowOffA + kk);
        #pragma unroll
        for (int mi = 0; mi < 3; ++mi) {
            a0r[mi] = *(const f16x8*)(A0 + mi * 16 * ND + rowOffA + kk);
            a1r[mi] = *(const f16x8*)(A1 + mi * 16 * ND + rowOffA + kk);
        }
        #pragma unroll
        for (int mi = 0; mi < 3; ++mi)
            #pragma unroll
            for (int nt = 0; nt < 4; ++nt)
                acc[0][mi][nt] = __builtin_amdgcn_mfma_f32_16x16x32_f16(a0r[mi], bfr[nt], acc[0][mi][nt], 0, 0, 0);
        #pragma unroll
        for (int mi = 0; mi < 3; ++mi)
            #pragma unroll
            for (int nt = 0; nt < 4; ++nt)
                acc[1][mi][nt] = __builtin_amdgcn_mfma_f32_16x16x32_f16(a1r[mi], bfr[nt], acc[1][mi][nt], 0, 0, 0);
    }

    // ---- wave-private epilogue ----
    char* waveE = smemE + wave * 8192;
    {   // zero E^T rows 48..63 once (chunks 6,7) — NaN guard for quadform pad
        f16x8 z = {(f16)0.f, (f16)0.f, (f16)0.f, (f16)0.f, (f16)0.f, (f16)0.f, (f16)0.f, (f16)0.f};
        int col = lane;
        *(f16x8*)(waveE + col * 128 + ((6 ^ (col & 7)) * 16)) = z;
        *(f16x8*)(waveE + col * 128 + ((7 ^ (col & 7)) * 16)) = z;
    }

    #pragma unroll
    for (int img = 0; img < 2; ++img) {
        const int ii = img ? i1 : i0;
        // -- per-row l2-norm reciprocal (rows >= 36 -> 0) --
        float rn[3][4];
        #pragma unroll
        for (int mi = 0; mi < 3; ++mi) {
            #pragma unroll
            for (int r = 0; r < 4; ++r) {
                int row = mi * 16 + quad * 4 + r;
                float ss = 0.f;
                #pragma unroll
                for (int nt = 0; nt < 4; ++nt) {
                    int col = nt * 16 + l16;
                    float v = acc[img][mi][nt][r];
                    float lv = v > 0.f ? v : 0.1f * v;
                    if (col < L) ss += lv * lv;
                }
                ss += __shfl_xor(ss, 1, 64);
                ss += __shfl_xor(ss, 2, 64);
                ss += __shfl_xor(ss, 4, 64);
                ss += __shfl_xor(ss, 8, 64);
                rn[mi][r] = (row < NR) ? 1.0f / (sqrtf(ss) + EPSF) : 0.f;
            }
        }
        // -- e = exp(9*an): write E^T f16 (swizzled); cs/nu per-col partials --
        float cs[4] = {0.f, 0.f, 0.f, 0.f}, nu[4] = {0.f, 0.f, 0.f, 0.f};
        #pragma unroll
        for (int mi = 0; mi < 3; ++mi) {
            #pragma unroll
            for (int nt = 0; nt < 4; ++nt) {
                int col = nt * 16 + l16;
                f16x4 ew;
                #pragma unroll
                for (int r = 0; r < 4; ++r) {
                    float v = acc[img][mi][nt][r];
                    float lv = v > 0.f ? v : 0.1f * v;
                    float e = expf(LAM_SM * ((col < L) ? lv * rn[mi][r] : 0.f));
                    ew[r] = (f16)e;
                    if (mi * 16 + quad * 4 + r < NR) { cs[nt] += e; nu[nt] += e * v; }
                }
                int c = mi * 2 + (quad >> 1);
                *(f16x4*)(waveE + col * 128 + ((c ^ (col & 7)) * 16) + (quad & 1) * 8) = ew;
            }
        }
        #pragma unroll
        for (int nt = 0; nt < 4; ++nt) {
            cs[nt] += __shfl_xor(cs[nt], 16, 64); cs[nt] += __shfl_xor(cs[nt], 32, 64);
            nu[nt] += __shfl_xor(nu[nt], 16, 64); nu[nt] += __shfl_xor(nu[nt], 32, 64);
        }
        // -- quadform: Y = M (global L2) x E^T (LDS), then qf = e . y --
        const f16* Mi = Mg16 + (size_t)ii * (MT * NW);
        f32x4 y[3][4];
        #pragma unroll
        for (int mi = 0; mi < 3; ++mi)
            #pragma unroll
            for (int nt = 0; nt < 4; ++nt)
                y[mi][nt] = (f32x4){0.f, 0.f, 0.f, 0.f};
        #pragma unroll
        for (int ks = 0; ks < 2; ++ks) {
            f16x8 aq[3];
            #pragma unroll
            for (int mi = 0; mi < 3; ++mi)
                aq[mi] = *(const f16x8*)(Mi + (mi * 16 + l16) * NW + ks * 32 + quad * 8);
            #pragma unroll
            for (int nt = 0; nt < 4; ++nt) {
                int col = nt * 16 + l16;
                int pch = (ks * 4 + quad) ^ (col & 7);
                f16x8 bq = *(const f16x8*)(waveE + col * 128 + pch * 16);
                #pragma unroll
                for (int mi = 0; mi < 3; ++mi)
                    y[mi][nt] = __builtin_amdgcn_mfma_f32_16x16x32_f16(aq[mi], bq, y[mi][nt], 0, 0, 0);
            }
        }
        float qf[4] = {0.f, 0.f, 0.f, 0.f};
        #pragma unroll
        for (int mi = 0; mi < 3; ++mi) {
            int row0 = mi * 16 + quad * 4;
            int c = row0 >> 3, sub = (row0 >> 2) & 1;
            #pragma unroll
            for (int nt = 0; nt < 4; ++nt) {
                int col = nt * 16 + l16;
                f16x4 ev = *(const f16x4*)(waveE + col * 128 + ((c ^ (col & 7)) * 16) + sub * 8);
                #pragma unroll
                for (int r = 0; r < 4; ++r) qf[nt] += y[mi][nt][r] * (float)ev[r];
            }
        }
        #pragma unroll
        for (int nt = 0; nt < 4; ++nt) {
            qf[nt] += __shfl_xor(qf[nt], 16, 64); qf[nt] += __shfl_xor(qf[nt], 32, 64);
        }
        // -- finalize: cosine row values, LSE over words, write score --
        float lse = 0.f;
        #pragma unroll
        for (int nt = 0; nt < 4; ++nt) {
            int col = nt * 16 + l16;
            float num  = nu[nt] / cs[nt];
            float nwei = sqrtf(fmaxf(qf[nt], 0.f)) / cs[nt];
            float nc   = ncap[j * NW + col];
            float rowv = num / fmaxf(nc * nwei, EPSF);
            lse += (col < L) ? expf(LAM_LSE * rowv) : 0.f;
        }
        lse += __shfl_xor(lse, 1, 64);
        lse += __shfl_xor(lse, 2, 64);
        lse += __shfl_xor(lse, 4, 64);
        lse += __shfl_xor(lse, 8, 64);
        if (lane == 0) scores[ii * NB + j] = logf(lse) / LAM_LSE;
    }
}

// ---------------- kernel C: contrastive loss reduction ----------------
__global__ __launch_bounds__(128) void loss_kernel(const float* __restrict__ S,
                                                   float* __restrict__ out) {
    __shared__ float part[NB];
    int t = threadIdx.x;
    float dii = S[t * NB + t];
    float rmax = 0.f, cmax = 0.f;
    for (int k = 0; k < NB; ++k) {
        if (k != t) {
            float vs = MARGINF + S[t * NB + k] - dii;
            rmax = fmaxf(rmax, fmaxf(vs, 0.f));
            float vi = MARGINF + S[k * NB + t] - dii;
            cmax = fmaxf(cmax, fmaxf(vi, 0.f));
        }
    }
    part[t] = rmax + cmax;
    __syncthreads();
    if (t == 0) {
        float sum = 0.f;
        for (int k = 0; k < NB; ++k) sum += part[k];
        out[0] = sum;
    }
}

extern "C" void kernel_launch(void* const* d_in, const int* in_sizes, int n_in,
                              void* d_out, int out_size, void* d_ws, size_t ws_size,
                              hipStream_t stream) {
    const float* im  = (const float*)d_in[0];
    const float* s   = (const float*)d_in[1];
    const int*   s_l = (const int*)d_in[2];

    float* scores = (float*)d_ws;                          // 16384 f
    float* ncap   = scores + NB * NB;                      // 8192 f
    f16*   Mg16   = (f16*)(ncap + NB * NW);                // 128*48*64 f16
    f16*   im16   = Mg16 + (size_t)NB * MT * NW;           // 128*48*1024 f16
    f16*   s16    = im16 + (size_t)NB * MT * ND;           // 128*64*1024 f16

    dim3 cgrid(NB, MT + NW);
    convert_kernel<<<cgrid, 256, 0, stream>>>(im, s, im16, s16, ncap);
    dim3 ggrid(NB, 3);
    gram16_kernel<<<ggrid, 256, 0, stream>>>(im16, Mg16);
    pair_mfma_kernel<<<2048, 256, 0, stream>>>(im16, s16, s_l, Mg16, ncap, scores);
    loss_kernel<<<1, NB, 0, stream>>>(scores, (float*)d_out);
}